// Round 3
// baseline (279.328 us; speedup 1.0000x reference)
//
#include <hip/hip_runtime.h>
#include <math.h>

#define T_LEN 512
#define H_HEADS 8
#define DK 64
#define LR 128      // L_TABLES * R = 8 * 16
#define NTOT 32     // M*B*H
#define TT 64       // t-tile size

__device__ __forceinline__ float fast_tanh(float x) {
    float e = __expf(2.0f * x);
    return 1.0f - 2.0f / (1.0f + e);
}

// K0: zero the output (harness poisons it; k_attn accumulates via atomics).
// out has exactly out_size elements; grid is sized as out_size/1024 by the
// launcher (out_size = 1,048,576 -> 1024 blocks x 256 thr x 4 floats).
__global__ __launch_bounds__(256) void k_zero(float* __restrict__ out) {
    int id = blockIdx.x * 256 + threadIdx.x;
    *(float4*)(out + (size_t)id * 4) = make_float4(0.f, 0.f, 0.f, 0.f);
}

// K1: per (n, 64-t tile): staged-transposed X^T in LDS, register-tiled
// projection GEMM, tanh, per-table softmax, transposed prob output [n][lr][t].
__global__ __launch_bounds__(256) void k_probs(
    const float* __restrict__ Khf, const float* __restrict__ Qhf,
    const float* __restrict__ planesT, const float* __restrict__ protosT,
    float* __restrict__ pKT, float* __restrict__ pQT)
{
    __shared__ float sm[23360];           // 93.4 KB
    float* planes = sm;                   // [64][32]    2048
    float* protos = sm + 2048;            // [4][16]     64
    float* XT     = sm + 2112;            // [64][132]   8448  (d-major, t2 0..127)
    float* xt     = sm + 10560;           // [128][33]   4224  (tanh'd proj)
    float* pbuf   = sm + 14784;           // [128][67]   8576

    const int bx = blockIdx.x;
    const int n  = bx >> 3;
    const int t0 = (bx & 7) * TT;
    const int g  = n >> 3, h = n & 7;
    const int tid = threadIdx.x;

#pragma unroll
    for (int m = 0; m < 8; ++m) planes[m * 256 + tid] = planesT[m * 256 + tid];
    if (tid < 64) protos[tid] = protosT[tid];

    // stage + transpose in one pass: read float4 rows, scatter-write X^T
#pragma unroll
    for (int m = 0; m < 8; ++m) {
        int fid = m * 256 + tid;
        int t2 = fid >> 4, c4 = fid & 15;
        const float* src = (t2 < 64 ? Khf : Qhf) +
            ((long)(g * T_LEN + t0 + (t2 & 63)) * H_HEADS + h) * DK + c4 * 4;
        float4 v = *(const float4*)src;
        XT[(c4 * 4 + 0) * 132 + t2] = v.x;
        XT[(c4 * 4 + 1) * 132 + t2] = v.y;
        XT[(c4 * 4 + 2) * 132 + t2] = v.z;
        XT[(c4 * 4 + 3) * 132 + t2] = v.w;
    }
    __syncthreads();

    // projection GEMM: proj[t2 0..127][j 0..31], K-dim d=64, 4x4 per thread
    {
        const int a4 = tid & 31;          // t2-block
        const int b4 = tid >> 5;          // j-block (0..7)
        float pr[4][4] = {};
#pragma unroll 8
        for (int d = 0; d < 64; ++d) {
            float4 a = *(const float4*)(XT + d * 132 + a4 * 4);
            float4 b = *(const float4*)(planes + d * 32 + b4 * 4);
            float av[4] = {a.x, a.y, a.z, a.w};
            float bv[4] = {b.x, b.y, b.z, b.w};
#pragma unroll
            for (int ii = 0; ii < 4; ++ii)
#pragma unroll
                for (int jj = 0; jj < 4; ++jj) pr[ii][jj] += av[ii] * bv[jj];
        }
#pragma unroll
        for (int ii = 0; ii < 4; ++ii)
#pragma unroll
            for (int jj = 0; jj < 4; ++jj)
                xt[(a4 * 4 + ii) * 33 + b4 * 4 + jj] = fast_tanh(pr[ii][jj]) * 0.125f;
    }
    __syncthreads();

    // per-table softmax over 16 corners; |logit| <= 0.5 so no max-subtract
    const int r = tid & 15, l = (tid >> 4) & 7, thi = tid >> 7;
    for (int side = 0; side < 2; ++side) {
        float p0 = protos[r], p1 = protos[16 + r], p2 = protos[32 + r], p3 = protos[48 + r];
#pragma unroll 4
        for (int w = 0; w < 32; ++w) {
            int tl = w * 2 + thi;
            const float* x = xt + (side * 64 + tl) * 33 + l * 4;
            float logit = x[0] * p0 + x[1] * p1 + x[2] * p2 + x[3] * p3;
            float e = __expf(logit);
            float s = e;
            s += __shfl_xor(s, 1, 16);
            s += __shfl_xor(s, 2, 16);
            s += __shfl_xor(s, 4, 16);
            s += __shfl_xor(s, 8, 16);
            pbuf[(l * 16 + r) * 67 + tl] = e / s;
        }
        __syncthreads();
        float* dst = side ? pQT : pKT;
#pragma unroll 4
        for (int w = 0; w < 32; ++w) {
            int idx = w * 256 + tid;
            int tl = idx & 63, lr = idx >> 6;
            dst[(long)(n * LR + lr) * T_LEN + t0 + tl] = pbuf[lr * 67 + tl];
        }
        __syncthreads();
    }
}

// K2: one wave per (n,lr): in-lane scan of 8 + wave shfl scan; qw = pQ/(A+eps)
__global__ __launch_bounds__(64) void k_cumsum(
    const float* __restrict__ pKT, float* __restrict__ pQT)
{
    const int lane = threadIdx.x;
    long base = (long)blockIdx.x * T_LEN + lane * 8;
    float4 ka = *(const float4*)(pKT + base);
    float4 kb = *(const float4*)(pKT + base + 4);
    float s[8];
    s[0] = ka.x;        s[1] = s[0] + ka.y; s[2] = s[1] + ka.z; s[3] = s[2] + ka.w;
    s[4] = s[3] + kb.x; s[5] = s[4] + kb.y; s[6] = s[5] + kb.z; s[7] = s[6] + kb.w;
    float tot = s[7];
#pragma unroll
    for (int off = 1; off < 64; off <<= 1) {
        float v = __shfl_up(tot, off, 64);
        if (lane >= off) tot += v;
    }
    float excl = tot - s[7];
    float4 qa = *(const float4*)(pQT + base);
    float4 qb = *(const float4*)(pQT + base + 4);
    float4 oa, ob;
    oa.x = qa.x / (excl + s[0] + 1e-6f);
    oa.y = qa.y / (excl + s[1] + 1e-6f);
    oa.z = qa.z / (excl + s[2] + 1e-6f);
    oa.w = qa.w / (excl + s[3] + 1e-6f);
    ob.x = qb.x / (excl + s[4] + 1e-6f);
    ob.y = qb.y / (excl + s[5] + 1e-6f);
    ob.z = qb.z / (excl + s[6] + 1e-6f);
    ob.w = qb.w / (excl + s[7] + 1e-6f);
    *(float4*)(pQT + base) = oa;
    *(float4*)(pQT + base + 4) = ob;
}

// K3: chunk-task parallel causal attention. Task = (n, rt 64-row tile, c 64-col
// chunk), 1152 uniform tasks, one 64-thread wave each, 8x8 register tiles.
// Computes S^T = K-chunk^T-dot-Q (row-contiguous store), then out += S V via
// atomics into zeroed out.
__global__ __launch_bounds__(64, 2) void k_attn(
    const float* __restrict__ qwT, const float* __restrict__ pKT,
    const float* __restrict__ Vhf, float* __restrict__ out)
{
    __shared__ float smA[4096];   // Qq [0..2047] + Kq [2048..4095]; ST aliases all
    __shared__ float Vs[4096];    // V chunk [t'][d], stride 64
    float* Qq = smA;
    float* Kq = smA + 2048;
    float* ST = smA;

    const int lane = threadIdx.x;
    const int ty = lane >> 3, tx = lane & 7;

    int tsk = blockIdx.x;
    int n = tsk / 36, rem = tsk % 36;
    int rt = 0;
    while (rem > rt) { rem -= rt + 1; ++rt; }
    const int c = rem;
    const int g = n >> 3, h = n & 7;

    // stage V chunk (64 rows x 64 d)
    const float* vsrc = Vhf + ((long)(g * T_LEN + c * 64) * H_HEADS + h) * DK;
#pragma unroll
    for (int m = 0; m < 16; ++m) {
        int fid = m * 64 + lane;
        int row = fid >> 4, c4 = fid & 15;
        *(float4*)(Vs + row * 64 + c4 * 4) = *(const float4*)(vsrc + row * 512 + c4 * 4);
    }

    // score: S^T[j][i] = sum_kk Kp[kk][j] * Qw[kk][i], kk streamed in 4 quarters
    float acc[8][8] = {};
    for (int qq = 0; qq < 4; ++qq) {
        __syncthreads();
        const float* qsrc = qwT + (long)(n * LR + qq * 32) * T_LEN + rt * 64;
        const float* ksrc = pKT + (long)(n * LR + qq * 32) * T_LEN + c * 64;
#pragma unroll
        for (int m = 0; m < 8; ++m) {
            int fid = m * 64 + lane;
            int row = fid >> 4, c4 = fid & 15;
            *(float4*)(Qq + row * 64 + c4 * 4) = *(const float4*)(qsrc + row * T_LEN + c4 * 4);
            *(float4*)(Kq + row * 64 + c4 * 4) = *(const float4*)(ksrc + row * T_LEN + c4 * 4);
        }
        __syncthreads();
#pragma unroll 4
        for (int kk = 0; kk < 32; ++kk) {
            float4 a0 = *(const float4*)(Kq + kk * 64 + ty * 8);
            float4 a1 = *(const float4*)(Kq + kk * 64 + ty * 8 + 4);
            float4 b0 = *(const float4*)(Qq + kk * 64 + tx * 8);
            float4 b1 = *(const float4*)(Qq + kk * 64 + tx * 8 + 4);
            float a[8] = {a0.x, a0.y, a0.z, a0.w, a1.x, a1.y, a1.z, a1.w};
            float b[8] = {b0.x, b0.y, b0.z, b0.w, b1.x, b1.y, b1.z, b1.w};
#pragma unroll
            for (int p = 0; p < 8; ++p)
#pragma unroll
                for (int q = 0; q < 8; ++q) acc[p][q] += a[p] * b[q];
        }
    }

    if (c == rt) {   // causal mask: keep key j <= query i
#pragma unroll
        for (int p = 0; p < 8; ++p)
#pragma unroll
            for (int q = 0; q < 8; ++q)
                if (ty * 8 + p > tx * 8 + q) acc[p][q] = 0.f;
    }

    __syncthreads();
#pragma unroll
    for (int p = 0; p < 8; ++p) {
        *(float4*)(ST + (ty * 8 + p) * 64 + tx * 8) =
            make_float4(acc[p][0], acc[p][1], acc[p][2], acc[p][3]);
        *(float4*)(ST + (ty * 8 + p) * 64 + tx * 8 + 4) =
            make_float4(acc[p][4], acc[p][5], acc[p][6], acc[p][7]);
    }
    __syncthreads();

    // PV: out[i][d] += sum_j S[i][j] * V[j][d], reading S^T rows as contraction
    float o[8][8] = {};
#pragma unroll 4
    for (int kk = 0; kk < 64; ++kk) {
        float4 a0 = *(const float4*)(ST + kk * 64 + ty * 8);
        float4 a1 = *(const float4*)(ST + kk * 64 + ty * 8 + 4);
        float4 b0 = *(const float4*)(Vs + kk * 64 + tx * 8);
        float4 b1 = *(const float4*)(Vs + kk * 64 + tx * 8 + 4);
        float a[8] = {a0.x, a0.y, a0.z, a0.w, a1.x, a1.y, a1.z, a1.w};
        float b[8] = {b0.x, b0.y, b0.z, b0.w, b1.x, b1.y, b1.z, b1.w};
#pragma unroll
        for (int p = 0; p < 8; ++p)
#pragma unroll
            for (int q = 0; q < 8; ++q) o[p][q] += a[p] * b[q];
    }

    float* obase = out + ((long)(g * T_LEN + rt * 64) * H_HEADS + h) * DK;
#pragma unroll
    for (int p = 0; p < 8; ++p)
#pragma unroll
        for (int q = 0; q < 8; ++q)
            atomicAdd(obase + (ty * 8 + p) * 512 + tx * 8 + q, o[p][q]);
}

extern "C" void kernel_launch(void* const* d_in, const int* in_sizes, int n_in,
                              void* d_out, int out_size, void* d_ws, size_t ws_size,
                              hipStream_t stream) {
    const float* Khf     = (const float*)d_in[0];
    const float* Vhf     = (const float*)d_in[1];
    const float* Qhf     = (const float*)d_in[2];
    const float* planesT = (const float*)d_in[3];
    const float* protosT = (const float*)d_in[4];
    float* outp = (float*)d_out;

    float* pKT = (float*)d_ws;                       // [32][128][512]
    float* pQT = pKT + (size_t)NTOT * LR * T_LEN;    // [32][128][512] -> qw in place

    // out_size = 1,048,576 floats; 256 thr x 4 floats per block
    int zblocks = out_size / 1024;                   // = 1024, exact
    k_zero<<<dim3(zblocks), dim3(256), 0, stream>>>(outp);
    k_probs<<<dim3(256), dim3(256), 0, stream>>>(Khf, Qhf, planesT, protosT, pKT, pQT);
    k_cumsum<<<dim3(4096), dim3(64), 0, stream>>>(pKT, pQT);
    k_attn<<<dim3(1152), dim3(64), 0, stream>>>(pQT, pKT, Vhf, outp);
}

// Round 4
// 127.226 us; speedup vs baseline: 2.1955x; 2.1955x over previous
//
#include <hip/hip_runtime.h>
#include <hip/hip_bf16.h>
#include <math.h>

#define T_LEN 512
#define H_HEADS 8
#define DK 64
#define LR 128      // L_TABLES * R = 8 * 16
#define NTOT 32     // M*B*H
#define TT 64       // t-tile size

typedef __attribute__((ext_vector_type(8))) short bf16x8;   // MFMA A/B frag (8 bf16)
typedef __attribute__((ext_vector_type(4))) float f32x4;    // MFMA C/D frag

__device__ __forceinline__ float fast_tanh(float x) {
    float e = __expf(2.0f * x);
    return 1.0f - 2.0f / (1.0f + e);
}

__device__ __forceinline__ unsigned short f2bf(float x) {
    union { float f; unsigned u; } v; v.f = x;
    unsigned r = v.u + 0x7FFF + ((v.u >> 16) & 1);   // RNE
    return (unsigned short)(r >> 16);
}

// K1: per (n, 64-t tile): staged-transposed X^T in LDS, register-tiled
// projection GEMM, tanh, per-table softmax, transposed prob output [n][lr][t].
__global__ __launch_bounds__(256) void k_probs(
    const float* __restrict__ Khf, const float* __restrict__ Qhf,
    const float* __restrict__ planesT, const float* __restrict__ protosT,
    float* __restrict__ pKT, float* __restrict__ pQT)
{
    __shared__ float sm[23360];
    float* planes = sm;                   // [64][32]    2048
    float* protos = sm + 2048;            // [4][16]     64
    float* XT     = sm + 2112;            // [64][132]   8448
    float* xt     = sm + 10560;           // [128][33]   4224
    float* pbuf   = sm + 14784;           // [128][67]   8576

    const int bx = blockIdx.x;
    const int n  = bx >> 3;
    const int t0 = (bx & 7) * TT;
    const int g  = n >> 3, h = n & 7;
    const int tid = threadIdx.x;

#pragma unroll
    for (int m = 0; m < 8; ++m) planes[m * 256 + tid] = planesT[m * 256 + tid];
    if (tid < 64) protos[tid] = protosT[tid];

#pragma unroll
    for (int m = 0; m < 8; ++m) {
        int fid = m * 256 + tid;
        int t2 = fid >> 4, c4 = fid & 15;
        const float* src = (t2 < 64 ? Khf : Qhf) +
            ((long)(g * T_LEN + t0 + (t2 & 63)) * H_HEADS + h) * DK + c4 * 4;
        float4 v = *(const float4*)src;
        XT[(c4 * 4 + 0) * 132 + t2] = v.x;
        XT[(c4 * 4 + 1) * 132 + t2] = v.y;
        XT[(c4 * 4 + 2) * 132 + t2] = v.z;
        XT[(c4 * 4 + 3) * 132 + t2] = v.w;
    }
    __syncthreads();

    {
        const int a4 = tid & 31;
        const int b4 = tid >> 5;
        float pr[4][4] = {};
#pragma unroll 8
        for (int d = 0; d < 64; ++d) {
            float4 a = *(const float4*)(XT + d * 132 + a4 * 4);
            float4 b = *(const float4*)(planes + d * 32 + b4 * 4);
            float av[4] = {a.x, a.y, a.z, a.w};
            float bv[4] = {b.x, b.y, b.z, b.w};
#pragma unroll
            for (int ii = 0; ii < 4; ++ii)
#pragma unroll
                for (int jj = 0; jj < 4; ++jj) pr[ii][jj] += av[ii] * bv[jj];
        }
#pragma unroll
        for (int ii = 0; ii < 4; ++ii)
#pragma unroll
            for (int jj = 0; jj < 4; ++jj)
                xt[(a4 * 4 + ii) * 33 + b4 * 4 + jj] = fast_tanh(pr[ii][jj]) * 0.125f;
    }
    __syncthreads();

    const int r = tid & 15, l = (tid >> 4) & 7, thi = tid >> 7;
    for (int side = 0; side < 2; ++side) {
        float p0 = protos[r], p1 = protos[16 + r], p2 = protos[32 + r], p3 = protos[48 + r];
#pragma unroll 4
        for (int w = 0; w < 32; ++w) {
            int tl = w * 2 + thi;
            const float* x = xt + (side * 64 + tl) * 33 + l * 4;
            float logit = x[0] * p0 + x[1] * p1 + x[2] * p2 + x[3] * p3;
            float e = __expf(logit);
            float s = e;
            s += __shfl_xor(s, 1, 16);
            s += __shfl_xor(s, 2, 16);
            s += __shfl_xor(s, 4, 16);
            s += __shfl_xor(s, 8, 16);
            pbuf[(l * 16 + r) * 67 + tl] = e / s;
        }
        __syncthreads();
        float* dst = side ? pQT : pKT;
#pragma unroll 4
        for (int w = 0; w < 32; ++w) {
            int idx = w * 256 + tid;
            int tl = idx & 63, lr = idx >> 6;
            dst[(long)(n * LR + lr) * T_LEN + t0 + tl] = pbuf[lr * 67 + tl];
        }
        __syncthreads();
    }
}

// K2: one wave per (n,lr): in-lane scan of 8 + wave shfl scan; qw = pQ/(A+eps)
__global__ __launch_bounds__(64) void k_cumsum(
    const float* __restrict__ pKT, float* __restrict__ pQT)
{
    const int lane = threadIdx.x;
    long base = (long)blockIdx.x * T_LEN + lane * 8;
    float4 ka = *(const float4*)(pKT + base);
    float4 kb = *(const float4*)(pKT + base + 4);
    float s[8];
    s[0] = ka.x;        s[1] = s[0] + ka.y; s[2] = s[1] + ka.z; s[3] = s[2] + ka.w;
    s[4] = s[3] + kb.x; s[5] = s[4] + kb.y; s[6] = s[5] + kb.z; s[7] = s[6] + kb.w;
    float tot = s[7];
#pragma unroll
    for (int off = 1; off < 64; off <<= 1) {
        float v = __shfl_up(tot, off, 64);
        if (lane >= off) tot += v;
    }
    float excl = tot - s[7];
    float4 qa = *(const float4*)(pQT + base);
    float4 qb = *(const float4*)(pQT + base + 4);
    float4 oa, ob;
    oa.x = qa.x / (excl + s[0] + 1e-6f);
    oa.y = qa.y / (excl + s[1] + 1e-6f);
    oa.z = qa.z / (excl + s[2] + 1e-6f);
    oa.w = qa.w / (excl + s[3] + 1e-6f);
    ob.x = qb.x / (excl + s[4] + 1e-6f);
    ob.y = qb.y / (excl + s[5] + 1e-6f);
    ob.z = qb.z / (excl + s[6] + 1e-6f);
    ob.w = qb.w / (excl + s[7] + 1e-6f);
    *(float4*)(pQT + base) = oa;
    *(float4*)(pQT + base + 4) = ob;
}

// K2b: transpose+convert to MFMA-friendly bf16 layouts:
//   qwB[n][t][lr], pKB[n][t][lr]  (A/B frags read 8 contiguous lr)
//   VBT[n][d][t]                  (PV B frag reads 8 contiguous t)
__global__ __launch_bounds__(256) void k_pack(
    const float* __restrict__ qwT, const float* __restrict__ pKT,
    const float* __restrict__ Vhf,
    unsigned short* __restrict__ qwB, unsigned short* __restrict__ pKB,
    unsigned short* __restrict__ VBT)
{
    __shared__ float buf[128 * 65];
    const int n = blockIdx.x >> 3, tile = blockIdx.x & 7;
    const int t0 = tile * 64;
    const int tid = threadIdx.x;
    const int g = n >> 3, h = n & 7;

    // ---- qw and pK: [lr][t] fp32 -> [t][lr] bf16 ----
    for (int sel = 0; sel < 2; ++sel) {
        const float* src = (sel ? pKT : qwT) + (size_t)n * LR * T_LEN + t0;
#pragma unroll
        for (int it = 0; it < 8; ++it) {          // 2048 float4 = 128x64
            int fid = it * 256 + tid;
            int lr = fid >> 4, c4 = fid & 15;
            float4 v = *(const float4*)(src + (size_t)lr * T_LEN + c4 * 4);
            buf[lr * 65 + c4 * 4 + 0] = v.x;
            buf[lr * 65 + c4 * 4 + 1] = v.y;
            buf[lr * 65 + c4 * 4 + 2] = v.z;
            buf[lr * 65 + c4 * 4 + 3] = v.w;
        }
        __syncthreads();
        unsigned* dst = (unsigned*)(sel ? pKB : qwB) + (size_t)n * 32768 + t0 * 64;
#pragma unroll
        for (int it = 0; it < 16; ++it) {         // 4096 bf16-pairs = 64t x 64 lr-pairs
            int fid = it * 256 + tid;
            int t = fid >> 6, lp = fid & 63;
            unsigned u0 = f2bf(buf[(2 * lp) * 65 + t]);
            unsigned u1 = f2bf(buf[(2 * lp + 1) * 65 + t]);
            dst[t * 64 + lp] = u0 | (u1 << 16);
        }
        __syncthreads();
    }

    // ---- V: [t][d] fp32 -> [d][t] bf16 ----
#pragma unroll
    for (int it = 0; it < 4; ++it) {              // 1024 float4 = 64x64
        int fid = it * 256 + tid;
        int t = fid >> 4, c4 = fid & 15;
        float4 v = *(const float4*)(Vhf + ((size_t)(g * T_LEN + t0 + t) * H_HEADS + h) * DK + c4 * 4);
        buf[(c4 * 4 + 0) * 65 + t] = v.x;
        buf[(c4 * 4 + 1) * 65 + t] = v.y;
        buf[(c4 * 4 + 2) * 65 + t] = v.z;
        buf[(c4 * 4 + 3) * 65 + t] = v.w;
    }
    __syncthreads();
    {
        unsigned* dst = (unsigned*)VBT + (size_t)n * 16384 + t0 / 2;
#pragma unroll
        for (int it = 0; it < 8; ++it) {          // 2048 pairs = 64d x 32
            int fid = it * 256 + tid;
            int d = fid >> 5, tp = (fid & 31) * 2;
            unsigned u0 = f2bf(buf[d * 65 + tp]);
            unsigned u1 = f2bf(buf[d * 65 + tp + 1]);
            dst[d * 256 + tp / 2] = u0 | (u1 << 16);
        }
    }
}

// K3: MFMA causal attention. Block = (n, rt); 4 waves = 4 16-row m-bands.
// Per 64-chunk: S = Qw*pK^T (16 mfma), mask, bf16 S -> LDS, O += S*V (8 mfma).
// O lives in C-frags across chunks; register prefetch of next chunk's K/V.
__global__ __launch_bounds__(256) void k_attn(
    const unsigned short* __restrict__ qwB, const unsigned short* __restrict__ pKB,
    const unsigned short* __restrict__ VBT, float* __restrict__ out)
{
    __shared__ __align__(16) short sm2[26624];    // 52 KB
    short* Qsh = sm2;            // [64][136] bf16: Qw rows [i][lr]
    short* Ksh = sm2 + 8704;     // [64][136] bf16: pK rows [j][lr]
    short* Ssh = sm2 + 17408;    // [64][72]  bf16: S rows [i][j]
    short* Vsh = sm2 + 22016;    // [64][72]  bf16: V^T rows [d][t']

    const int n = blockIdx.x >> 3, rt = blockIdx.x & 7;
    const int g = n >> 3, h = n & 7;
    const int tid = threadIdx.x;
    const int w = tid >> 6, lane = tid & 63;
    const int m16 = lane & 15, q = lane >> 4;     // quad 0..3

    // stage Qw tile once: rows i of qwB[n][rt*64+i][0..128]
    const uint4* qg = (const uint4*)qwB + (size_t)n * 8192 + rt * 1024;
#pragma unroll
    for (int it = 0; it < 4; ++it) {
        int fid = it * 256 + tid;
        int i = fid >> 4, seg = fid & 15;
        *(uint4*)(Qsh + i * 136 + seg * 8) = qg[i * 16 + seg];
    }

    const uint4* kg = (const uint4*)pKB + (size_t)n * 8192;
    const uint4* vg = (const uint4*)VBT + (size_t)n * 4096;
    uint4 pk[4], pv[2];
    auto pref = [&](int c) {
#pragma unroll
        for (int it = 0; it < 4; ++it) {
            int fid = it * 256 + tid;
            pk[it] = kg[c * 1024 + (fid >> 4) * 16 + (fid & 15)];
        }
#pragma unroll
        for (int it = 0; it < 2; ++it) {
            int fid = it * 256 + tid;
            pv[it] = vg[(fid >> 3) * 64 + c * 8 + (fid & 7)];
        }
    };

    f32x4 o[4];
    o[0] = o[1] = o[2] = o[3] = (f32x4){0.f, 0.f, 0.f, 0.f};

    pref(0);
    for (int c = 0; c <= rt; ++c) {
        __syncthreads();                 // prior chunk's LDS reads done (also Q stage, 1st iter)
#pragma unroll
        for (int it = 0; it < 4; ++it) {
            int fid = it * 256 + tid;
            *(uint4*)(Ksh + (fid >> 4) * 136 + (fid & 15) * 8) = pk[it];
        }
#pragma unroll
        for (int it = 0; it < 2; ++it) {
            int fid = it * 256 + tid;
            *(uint4*)(Vsh + (fid >> 3) * 72 + (fid & 7) * 8) = pv[it];
        }
        __syncthreads();
        if (c < rt) pref(c + 1);         // hide global latency under compute

        // S^(m-band w, n-bands 0..3) = Qw * pK^T, K-dim = 128 in 4 steps
        f32x4 s[4];
        s[0] = s[1] = s[2] = s[3] = (f32x4){0.f, 0.f, 0.f, 0.f};
#pragma unroll
        for (int st = 0; st < 4; ++st) {
            bf16x8 a = *(const bf16x8*)(Qsh + (w * 16 + m16) * 136 + st * 32 + q * 8);
#pragma unroll
            for (int nb = 0; nb < 4; ++nb) {
                bf16x8 b = *(const bf16x8*)(Ksh + (nb * 16 + m16) * 136 + st * 32 + q * 8);
                s[nb] = __builtin_amdgcn_mfma_f32_16x16x32_bf16(a, b, s[nb], 0, 0, 0);
            }
        }

        if (c == rt) {                   // causal mask: keep j <= i (tile-local)
#pragma unroll
            for (int nb = 0; nb < 4; ++nb)
#pragma unroll
                for (int r = 0; r < 4; ++r)
                    if (nb * 16 + m16 > w * 16 + q * 4 + r) s[nb][r] = 0.f;
        }

        // C-layout -> A-layout via LDS (wave-private 16-row slice; no barrier)
#pragma unroll
        for (int nb = 0; nb < 4; ++nb)
#pragma unroll
            for (int r = 0; r < 4; ++r)
                Ssh[(w * 16 + q * 4 + r) * 72 + nb * 16 + m16] = (short)f2bf(s[nb][r]);

        // O += S * V, K-dim = 64 in 2 steps
#pragma unroll
        for (int st = 0; st < 2; ++st) {
            bf16x8 a = *(const bf16x8*)(Ssh + (w * 16 + m16) * 72 + st * 32 + q * 8);
#pragma unroll
            for (int nb = 0; nb < 4; ++nb) {
                bf16x8 b = *(const bf16x8*)(Vsh + (nb * 16 + m16) * 72 + st * 32 + q * 8);
                o[nb] = __builtin_amdgcn_mfma_f32_16x16x32_bf16(a, b, o[nb], 0, 0, 0);
            }
        }
    }

    // store O: row t = rt*64 + w*16 + q*4 + r, col d = nb*16 + m16
    float* ob = out + ((size_t)(g * T_LEN + rt * 64 + w * 16 + q * 4) * H_HEADS + h) * DK;
#pragma unroll
    for (int r = 0; r < 4; ++r)
#pragma unroll
        for (int nb = 0; nb < 4; ++nb)
            ob[r * (H_HEADS * DK) + nb * 16 + m16] = o[nb][r];
}

extern "C" void kernel_launch(void* const* d_in, const int* in_sizes, int n_in,
                              void* d_out, int out_size, void* d_ws, size_t ws_size,
                              hipStream_t stream) {
    const float* Khf     = (const float*)d_in[0];
    const float* Vhf     = (const float*)d_in[1];
    const float* Qhf     = (const float*)d_in[2];
    const float* planesT = (const float*)d_in[3];
    const float* protosT = (const float*)d_in[4];
    float* outp = (float*)d_out;

    const size_t NE = (size_t)NTOT * LR * T_LEN;      // 2,097,152
    float* pKT = (float*)d_ws;                        // fp32 [n][lr][t]
    float* qwT = pKT + NE;                            // fp32 [n][lr][t] (pQ -> qw in place)
    unsigned short* qwB = (unsigned short*)(qwT + NE);  // bf16 [n][t][lr]
    unsigned short* pKB = qwB + NE;                     // bf16 [n][t][lr]
    unsigned short* VBT = pKB + NE;                     // bf16 [n][d][t]

    k_probs<<<dim3(256), dim3(256), 0, stream>>>(Khf, Qhf, planesT, protosT, pKT, qwT);
    k_cumsum<<<dim3(4096), dim3(64), 0, stream>>>(pKT, qwT);
    k_pack<<<dim3(256), dim3(256), 0, stream>>>(qwT, pKT, Vhf, qwB, pKB, VBT);
    k_attn<<<dim3(256), dim3(256), 0, stream>>>(qwB, pKB, VBT, outp);
}

// Round 5
// 121.961 us; speedup vs baseline: 2.2903x; 1.0432x over previous
//
#include <hip/hip_runtime.h>
#include <hip/hip_bf16.h>
#include <math.h>

#define T_LEN 512
#define H_HEADS 8
#define DK 64
#define LR 128      // L_TABLES * R = 8 * 16
#define NTOT 32     // M*B*H
#define TT 64       // t-tile size

typedef __attribute__((ext_vector_type(8))) short bf16x8;   // MFMA A/B frag (8 bf16)
typedef __attribute__((ext_vector_type(4))) float f32x4;    // MFMA C/D frag

__device__ __forceinline__ float fast_tanh(float x) {
    float e = __expf(2.0f * x);
    return 1.0f - 2.0f / (1.0f + e);
}

__device__ __forceinline__ unsigned f2bf(float x) {
    union { float f; unsigned u; } v; v.f = x;
    unsigned r = v.u + 0x7FFF + ((v.u >> 16) & 1);   // RNE
    return r >> 16;
}

// K1: per (n, 64-t tile): projections -> tanh -> per-table softmax, fp32 probs
// [n][lr][t]; also packs V to bf16 VBT[n][d][t] (coalesced).
__global__ __launch_bounds__(256) void k_probs(
    const float* __restrict__ Khf, const float* __restrict__ Qhf,
    const float* __restrict__ Vhf,
    const float* __restrict__ planesT, const float* __restrict__ protosT,
    float* __restrict__ pKT, float* __restrict__ pQT,
    unsigned short* __restrict__ VBT)
{
    __shared__ float sm[23360];
    float* planes = sm;                   // [64][32]    2048
    float* protos = sm + 2048;            // [4][16]     64
    float* XT     = sm + 2112;            // [64][132]   8448
    float* xt     = sm + 10560;           // [128][33]   4224
    float* pbuf   = sm + 14784;           // [128][67]   8576

    const int bx = blockIdx.x;
    const int n  = bx >> 3;
    const int t0 = (bx & 7) * TT;
    const int g  = n >> 3, h = n & 7;
    const int tid = threadIdx.x;

#pragma unroll
    for (int m = 0; m < 8; ++m) planes[m * 256 + tid] = planesT[m * 256 + tid];
    if (tid < 64) protos[tid] = protosT[tid];

#pragma unroll
    for (int m = 0; m < 8; ++m) {
        int fid = m * 256 + tid;
        int t2 = fid >> 4, c4 = fid & 15;
        const float* src = (t2 < 64 ? Khf : Qhf) +
            ((long)(g * T_LEN + t0 + (t2 & 63)) * H_HEADS + h) * DK + c4 * 4;
        float4 v = *(const float4*)src;
        XT[(c4 * 4 + 0) * 132 + t2] = v.x;
        XT[(c4 * 4 + 1) * 132 + t2] = v.y;
        XT[(c4 * 4 + 2) * 132 + t2] = v.z;
        XT[(c4 * 4 + 3) * 132 + t2] = v.w;
    }
    __syncthreads();

    {
        const int a4 = tid & 31;
        const int b4 = tid >> 5;
        float pr[4][4] = {};
#pragma unroll 8
        for (int d = 0; d < 64; ++d) {
            float4 a = *(const float4*)(XT + d * 132 + a4 * 4);
            float4 b = *(const float4*)(planes + d * 32 + b4 * 4);
            float av[4] = {a.x, a.y, a.z, a.w};
            float bv[4] = {b.x, b.y, b.z, b.w};
#pragma unroll
            for (int ii = 0; ii < 4; ++ii)
#pragma unroll
                for (int jj = 0; jj < 4; ++jj) pr[ii][jj] += av[ii] * bv[jj];
        }
#pragma unroll
        for (int ii = 0; ii < 4; ++ii)
#pragma unroll
            for (int jj = 0; jj < 4; ++jj)
                xt[(a4 * 4 + ii) * 33 + b4 * 4 + jj] = fast_tanh(pr[ii][jj]) * 0.125f;
    }
    __syncthreads();

    const int r = tid & 15, l = (tid >> 4) & 7, thi = tid >> 7;
    for (int side = 0; side < 2; ++side) {
        float p0 = protos[r], p1 = protos[16 + r], p2 = protos[32 + r], p3 = protos[48 + r];
#pragma unroll 4
        for (int w = 0; w < 32; ++w) {
            int tl = w * 2 + thi;
            const float* x = xt + (side * 64 + tl) * 33 + l * 4;
            float logit = x[0] * p0 + x[1] * p1 + x[2] * p2 + x[3] * p3;
            float e = __expf(logit);
            float s = e;
            s += __shfl_xor(s, 1, 16);
            s += __shfl_xor(s, 2, 16);
            s += __shfl_xor(s, 4, 16);
            s += __shfl_xor(s, 8, 16);
            pbuf[(l * 16 + r) * 67 + tl] = e / s;
        }
        __syncthreads();
        float* dst = side ? pQT : pKT;
#pragma unroll 4
        for (int w = 0; w < 32; ++w) {
            int idx = w * 256 + tid;
            int tl = idx & 63, lr = idx >> 6;
            dst[(long)(n * LR + lr) * T_LEN + t0 + tl] = pbuf[lr * 67 + tl];
        }
        __syncthreads();
    }

    // ---- V pack: [t][d] fp32 -> VBT[n][d][t] bf16 (transpose via LDS) ----
    float* vb = XT;   // reuse (64 x 65 floats)
#pragma unroll
    for (int it = 0; it < 4; ++it) {
        int fid = it * 256 + tid;
        int t = fid >> 4, c4 = fid & 15;
        float4 v = *(const float4*)(Vhf + ((size_t)(g * T_LEN + t0 + t) * H_HEADS + h) * DK + c4 * 4);
        vb[(c4 * 4 + 0) * 65 + t] = v.x;
        vb[(c4 * 4 + 1) * 65 + t] = v.y;
        vb[(c4 * 4 + 2) * 65 + t] = v.z;
        vb[(c4 * 4 + 3) * 65 + t] = v.w;
    }
    __syncthreads();
    {
        unsigned* dst = (unsigned*)VBT + (size_t)n * 16384 + t0 / 2;
#pragma unroll
        for (int it = 0; it < 8; ++it) {
            int fid = it * 256 + tid;
            int d = fid >> 5, tp = (fid & 31) * 2;
            unsigned u0 = f2bf(vb[d * 65 + tp]);
            unsigned u1 = f2bf(vb[d * 65 + tp + 1]);
            dst[d * 256 + tp / 2] = u0 | (u1 << 16);
        }
    }
}

// K2: one wave per (n,lr): in-lane scan of 8 + wave shfl scan; writes
// qw = pQ/(A+eps) and pK directly as bf16 [n][lr][t] (coalesced uint4).
__global__ __launch_bounds__(64) void k_cumsum(
    const float* __restrict__ pKT, const float* __restrict__ pQT,
    unsigned short* __restrict__ qwB, unsigned short* __restrict__ pKB)
{
    const int lane = threadIdx.x;
    const int bid = blockIdx.x;                 // n*128 + lr
    long base = (long)bid * T_LEN + lane * 8;
    float4 ka = *(const float4*)(pKT + base);
    float4 kb = *(const float4*)(pKT + base + 4);
    float s[8];
    s[0] = ka.x;        s[1] = s[0] + ka.y; s[2] = s[1] + ka.z; s[3] = s[2] + ka.w;
    s[4] = s[3] + kb.x; s[5] = s[4] + kb.y; s[6] = s[5] + kb.z; s[7] = s[6] + kb.w;
    float tot = s[7];
#pragma unroll
    for (int off = 1; off < 64; off <<= 1) {
        float v = __shfl_up(tot, off, 64);
        if (lane >= off) tot += v;
    }
    float excl = tot - s[7];
    float4 qa = *(const float4*)(pQT + base);
    float4 qb = *(const float4*)(pQT + base + 4);
    float o[8];
    o[0] = qa.x / (excl + s[0] + 1e-6f);
    o[1] = qa.y / (excl + s[1] + 1e-6f);
    o[2] = qa.z / (excl + s[2] + 1e-6f);
    o[3] = qa.w / (excl + s[3] + 1e-6f);
    o[4] = qb.x / (excl + s[4] + 1e-6f);
    o[5] = qb.y / (excl + s[5] + 1e-6f);
    o[6] = qb.z / (excl + s[6] + 1e-6f);
    o[7] = qb.w / (excl + s[7] + 1e-6f);

    uint4 qv, kv;
    qv.x = f2bf(o[0]) | (f2bf(o[1]) << 16);
    qv.y = f2bf(o[2]) | (f2bf(o[3]) << 16);
    qv.z = f2bf(o[4]) | (f2bf(o[5]) << 16);
    qv.w = f2bf(o[6]) | (f2bf(o[7]) << 16);
    kv.x = f2bf(ka.x) | (f2bf(ka.y) << 16);
    kv.y = f2bf(ka.z) | (f2bf(ka.w) << 16);
    kv.z = f2bf(kb.x) | (f2bf(kb.y) << 16);
    kv.w = f2bf(kb.z) | (f2bf(kb.w) << 16);
    *(uint4*)((unsigned*)qwB + (size_t)bid * 256 + lane * 4) = qv;
    *(uint4*)((unsigned*)pKB + (size_t)bid * 256 + lane * 4) = kv;
}

// K3: MFMA causal attention. Block = (n, rt), 512 thr = 2 wave-groups x 4
// m-band waves. Group g processes chunks c == g (mod 2); private Ksh/Vsh/Ssh;
// O partials combined via LDS at the end. Q A-frags live in registers.
__global__ __launch_bounds__(512) void k_attn(
    const unsigned short* __restrict__ qwB, const unsigned short* __restrict__ pKB,
    const unsigned short* __restrict__ VBT, float* __restrict__ out)
{
    __shared__ __align__(16) short sm2[44544];     // 87 KB
    short* Qsh  = sm2;                 // [64][136]; aliased as Obuf f32 [64][68] later
    short* Ksh0 = sm2 + 8704;          // [64][136] : rows j (t'), cols lr
    short* Ksh1 = sm2 + 17408;
    short* Vsh0 = sm2 + 26112;         // [64][72]  : rows d, cols t'
    short* Vsh1 = sm2 + 30720;
    short* Ssh0 = sm2 + 35328;         // [64][72]  : rows i, cols j
    short* Ssh1 = sm2 + 39936;
    float* Obuf = (float*)sm2;         // [64][68]

    const int n = blockIdx.x >> 3, rt = blockIdx.x & 7;
    const int g = n >> 3, h = n & 7;
    const int tid = threadIdx.x;
    const int wave = tid >> 6, wg = wave >> 2, w = wave & 3;
    const int lane = tid & 63, m16 = lane & 15, q = lane >> 4;
    const int gtid = tid & 255;

    short* Ksh = wg ? Ksh1 : Ksh0;
    short* Vsh = wg ? Vsh1 : Vsh0;
    short* Ssh = wg ? Ssh1 : Ssh0;

    const unsigned short* kq = qwB + (size_t)n * 65536;   // [lr][t]
    const unsigned short* kk = pKB + (size_t)n * 65536;   // [lr][t]
    const unsigned short* kv = VBT + (size_t)n * 32768;   // [d][t]

    // stage Q: transpose [lr][t-span] -> Qsh[t_local][lr]
#pragma unroll
    for (int it = 0; it < 2; ++it) {
        int fid = it * 512 + tid;                 // 0..1023 = 128 lr x 8 seg
        int lr = fid >> 3, seg = fid & 7;
        uint4 u = *(const uint4*)(kq + (size_t)lr * 512 + rt * 64 + seg * 8);
        unsigned uu[4] = {u.x, u.y, u.z, u.w};
#pragma unroll
        for (int p = 0; p < 4; ++p) {
            Qsh[(seg * 8 + 2 * p) * 136 + lr]     = (short)(uu[p] & 0xFFFFu);
            Qsh[(seg * 8 + 2 * p + 1) * 136 + lr] = (short)(uu[p] >> 16);
        }
    }
    __syncthreads();
    bf16x8 qa[4];
#pragma unroll
    for (int st = 0; st < 4; ++st)
        qa[st] = *(const bf16x8*)(Qsh + (w * 16 + m16) * 136 + st * 32 + q * 8);

    uint4 pk[4], pv[2];
    auto pref = [&](int c) {
#pragma unroll
        for (int it = 0; it < 4; ++it) {
            int fid = it * 256 + gtid;
            pk[it] = *(const uint4*)(kk + (size_t)(fid >> 3) * 512 + c * 64 + (fid & 7) * 8);
        }
#pragma unroll
        for (int it = 0; it < 2; ++it) {
            int fid = it * 256 + gtid;
            pv[it] = *(const uint4*)(kv + (size_t)(fid >> 3) * 512 + c * 64 + (fid & 7) * 8);
        }
    };

    f32x4 o[4];
    o[0] = o[1] = o[2] = o[3] = (f32x4){0.f, 0.f, 0.f, 0.f};

    if (wg <= rt) pref(wg);
    const int rounds = (rt >> 1) + 1;
    for (int r = 0; r < rounds; ++r) {
        const int c = 2 * r + wg;
        const bool act = (c <= rt);
        __syncthreads();                           // prior round's LDS reads done
        if (act) {
            // K: scatter-transpose [lr][t'] regs -> Ksh[j][lr]
#pragma unroll
            for (int it = 0; it < 4; ++it) {
                int fid = it * 256 + gtid;
                int lr = fid >> 3, seg = fid & 7;
                unsigned uu[4] = {pk[it].x, pk[it].y, pk[it].z, pk[it].w};
#pragma unroll
                for (int p = 0; p < 4; ++p) {
                    Ksh[(seg * 8 + 2 * p) * 136 + lr]     = (short)(uu[p] & 0xFFFFu);
                    Ksh[(seg * 8 + 2 * p + 1) * 136 + lr] = (short)(uu[p] >> 16);
                }
            }
            // V: already [d][t'] — direct b128 rows
            *(uint4*)(Vsh + (gtid >> 3) * 72 + (gtid & 7) * 8) = pv[0];
            *(uint4*)(Vsh + ((gtid + 256) >> 3) * 72 + (gtid & 7) * 8) = pv[1];
        }
        __syncthreads();
        if (c + 2 <= rt) pref(c + 2);              // overlap next loads with compute
        if (act) {
            f32x4 s[4];
            s[0] = s[1] = s[2] = s[3] = (f32x4){0.f, 0.f, 0.f, 0.f};
#pragma unroll
            for (int st = 0; st < 4; ++st)
#pragma unroll
                for (int nb = 0; nb < 4; ++nb) {
                    bf16x8 b = *(const bf16x8*)(Ksh + (nb * 16 + m16) * 136 + st * 32 + q * 8);
                    s[nb] = __builtin_amdgcn_mfma_f32_16x16x32_bf16(qa[st], b, s[nb], 0, 0, 0);
                }
            if (c == rt) {                         // causal: keep j <= i
#pragma unroll
                for (int nb = 0; nb < 4; ++nb)
#pragma unroll
                    for (int rr = 0; rr < 4; ++rr)
                        if (nb * 16 + m16 > w * 16 + q * 4 + rr) s[nb][rr] = 0.f;
            }
            // C-layout -> A-layout via wave-private Ssh rows (round-half-up bf16)
#pragma unroll
            for (int nb = 0; nb < 4; ++nb)
#pragma unroll
                for (int rr = 0; rr < 4; ++rr) {
                    union { float f; unsigned u; } cv; cv.f = s[nb][rr];
                    Ssh[(w * 16 + q * 4 + rr) * 72 + nb * 16 + m16] =
                        (short)((cv.u + 0x8000u) >> 16);
                }
#pragma unroll
            for (int st = 0; st < 2; ++st) {
                bf16x8 a = *(const bf16x8*)(Ssh + (w * 16 + m16) * 72 + st * 32 + q * 8);
#pragma unroll
                for (int nb = 0; nb < 4; ++nb) {
                    bf16x8 b = *(const bf16x8*)(Vsh + (nb * 16 + m16) * 72 + st * 32 + q * 8);
                    o[nb] = __builtin_amdgcn_mfma_f32_16x16x32_bf16(a, b, o[nb], 0, 0, 0);
                }
            }
        }
    }

    __syncthreads();                               // all compute done; Qsh -> Obuf
    if (wg == 1) {
#pragma unroll
        for (int nb = 0; nb < 4; ++nb)
#pragma unroll
            for (int rr = 0; rr < 4; ++rr)
                Obuf[(w * 16 + q * 4 + rr) * 68 + nb * 16 + m16] = o[nb][rr];
    }
    __syncthreads();
    if (wg == 0) {
        float* ob = out + ((size_t)(g * T_LEN + rt * 64 + w * 16 + q * 4) * H_HEADS + h) * DK;
#pragma unroll
        for (int rr = 0; rr < 4; ++rr)
#pragma unroll
            for (int nb = 0; nb < 4; ++nb)
                ob[rr * (H_HEADS * DK) + nb * 16 + m16] =
                    o[nb][rr] + Obuf[(w * 16 + q * 4 + rr) * 68 + nb * 16 + m16];
    }
}

extern "C" void kernel_launch(void* const* d_in, const int* in_sizes, int n_in,
                              void* d_out, int out_size, void* d_ws, size_t ws_size,
                              hipStream_t stream) {
    const float* Khf     = (const float*)d_in[0];
    const float* Vhf     = (const float*)d_in[1];
    const float* Qhf     = (const float*)d_in[2];
    const float* planesT = (const float*)d_in[3];
    const float* protosT = (const float*)d_in[4];
    float* outp = (float*)d_out;

    const size_t NE = (size_t)NTOT * LR * T_LEN;        // 2,097,152
    float* pKT = (float*)d_ws;                          // fp32 [n][lr][t]
    float* pQT = pKT + NE;                              // fp32 [n][lr][t]
    unsigned short* qwB = (unsigned short*)(pQT + NE);  // bf16 [n][lr][t]
    unsigned short* pKB = qwB + NE;                     // bf16 [n][lr][t]
    unsigned short* VBT = pKB + NE;                     // bf16 [n][d][t]

    k_probs<<<dim3(256), dim3(256), 0, stream>>>(Khf, Qhf, Vhf, planesT, protosT, pKT, pQT, VBT);
    k_cumsum<<<dim3(4096), dim3(64), 0, stream>>>(pKT, pQT, qwB, pKB);
    k_attn<<<dim3(256), dim3(512), 0, stream>>>(qwB, pKB, VBT, outp);
}